// Round 3
// baseline (321.663 us; speedup 1.0000x reference)
//
#include <hip/hip_runtime.h>

// B=8, T=64, N=512, D=64, K=8 heads, d=8.
// One workgroup (256 thr = 4 waves) per (b,n). Full fusion in LDS.
// R3: weights pre-converted to bf16 wT[c][k] in d_ws by a prep kernel;
// B-fragments read directly from global (L2-resident). QKV fused (shared
// A-frags). 2 barriers total. Softmax denom via ones-column in PV MFMA.
// LDS 43.7 KB -> 3 blocks/CU.

#define Bb 8
#define Tt 64
#define Nn 512
#define Dd 64

typedef unsigned short u16;
typedef unsigned int u32;
typedef __bf16 bf16x8 __attribute__((ext_vector_type(8)));
typedef float f32x4 __attribute__((ext_vector_type(4)));
typedef short s16x8 __attribute__((ext_vector_type(8)));

#define HS 136   // h row stride (shorts): 68 dw, %32=4 -> 2-way max (free)
#define QS 68    // qb/kb/vT/attnout/P stride: 34 dw, %32=2 -> 2-way (free)

// fused scale: 1/sqrt(8) * log2(e), applied to q at store; softmax uses exp2
#define QSCALE 0.51006977f

// ws layout (u16): wqT[64][128]@0, wkT@8192, wvT@16384, w1T[64][64]@24576, w2T@28672
#define WQ_OFF 0
#define WK_OFF 8192
#define WV_OFF 16384
#define W1_OFF 24576
#define W2_OFF 28672

__device__ inline u16 f2bf(float f) {             // fp32 -> bf16 RNE
    u32 x = __float_as_uint(f);
    x += 0x7fffu + ((x >> 16) & 1u);
    return (u16)(x >> 16);
}
__device__ inline bf16x8 ldf(const u16* p) { return *(const bf16x8*)p; }
__device__ inline bf16x8 zf8() {
    s16x8 z = {0, 0, 0, 0, 0, 0, 0, 0};
    return __builtin_bit_cast(bf16x8, z);
}

// ---------------- prep: fp32 weights -> bf16 wT[c][k] in ws ----------------
__global__ __launch_bounds__(256)
void prep_weights(const float* __restrict__ Wq, const float* __restrict__ Wk,
                  const float* __restrict__ Wv, const float* __restrict__ W1,
                  const float* __restrict__ W2, u16* __restrict__ ws) {
    int t = blockIdx.x * 256 + threadIdx.x;       // 0..32767
    if (t < 24576) {                              // three 128x64 matrices
        int m = t >> 13, r = t & 8191;            // r: row-major idx in W[f][c]
        const float* W = (m == 0) ? Wq : (m == 1) ? Wk : Wv;
        int f = r >> 6, c = r & 63;
        ws[m * 8192 + c * 128 + f] = f2bf(W[r]);  // coalesced read
    } else {                                      // two 64x64 matrices
        int t2 = t - 24576;
        int m = t2 >> 12, r = t2 & 4095;
        const float* W = m ? W2 : W1;
        int f = r >> 6, c = r & 63;
        ws[24576 + m * 4096 + c * 64 + f] = f2bf(W[r]);
    }
}

// ---------------- FFN gemm: A[64][As] LDS @ Wg[64][64] global ----------------
// MODE 0: relu -> bf16 LDS (stride Os); MODE 1: no relu -> fp32 global.
template<int MODE>
__device__ inline void mfma_gemm64(const u16* __restrict__ A, int As,
                                   const u16* __restrict__ Wg,
                                   const float* __restrict__ bias,
                                   u16* __restrict__ O, int Os,
                                   float* __restrict__ G,
                                   int w, int lane) {
    const int l15 = lane & 15, qd = lane >> 4;
    f32x4 acc[4];
#pragma unroll
    for (int ct = 0; ct < 4; ++ct) {
        float bv = bias[16 * ct + l15];
        acc[ct] = (f32x4){bv, bv, bv, bv};
    }
    const u16* arow = &A[(16 * w + l15) * As];
#pragma unroll
    for (int k0 = 0; k0 < 64; k0 += 32) {
        bf16x8 af = ldf(arow + k0 + qd * 8);
#pragma unroll
        for (int ct = 0; ct < 4; ++ct) {
            bf16x8 bfr = ldf(&Wg[(16 * ct + l15) * 64 + k0 + qd * 8]);
            acc[ct] = __builtin_amdgcn_mfma_f32_16x16x32_bf16(af, bfr, acc[ct], 0, 0, 0);
        }
    }
#pragma unroll
    for (int ct = 0; ct < 4; ++ct) {
        const int col = 16 * ct + l15;
#pragma unroll
        for (int r = 0; r < 4; ++r) {
            const int row = 16 * w + 4 * qd + r;
            float v = acc[ct][r];
            if (MODE == 0) { v = fmaxf(v, 0.f); O[row * Os + col] = f2bf(v); }
            else           { G[(size_t)row * (Nn * Dd) + col] = v; }
        }
    }
}

__global__ __launch_bounds__(256, 3)
void ta_fused_kernel(const float* __restrict__ x,  const float* __restrict__ ste,
                     const float* __restrict__ bq, const float* __restrict__ bk,
                     const float* __restrict__ bv_, const float* __restrict__ b1,
                     const float* __restrict__ b2, const u16* __restrict__ wsr,
                     float* __restrict__ out) {
    // LDS map (shorts), total 21828 (43656 B) -> 3 blocks/CU:
    //   h    [64][136] @ 0      (dead after QKV)
    //     attnout [64][68] @ 0         (overlay)
    //     P 4x[16][68]     @ 4352      (overlay, wave-private slices)
    //   qb   [64][68]  @ 8704   (abuf overlays after attention, same-wave rows)
    //   kb   [64][68]  @ 13056
    //   vT   [65][68]  @ 17408  (row 64 = ones column for softmax denom)
    __shared__ __align__(16) u16 sm[21828];
    u16* h       = sm;
    u16* qb      = sm + 8704;
    u16* kb      = sm + 13056;
    u16* vT      = sm + 17408;
    u16* attnout = sm;
    u16* abuf    = qb;

    const int tid  = threadIdx.x;
    const int w    = tid >> 6;
    const int lane = tid & 63;
    const int l15  = lane & 15, qd = lane >> 4;
    const int bid  = blockIdx.x;
    const int b = bid >> 9, n = bid & 511;

    const float* xb = x   + (((size_t)b * Tt) * Nn + n) * Dd;
    const float* sb = ste + (((size_t)b * Tt) * Nn + n) * Dd;
    const u16* wq = wsr + WQ_OFF;
    const u16* wk = wsr + WK_OFF;
    const u16* wv = wsr + WV_OFF;

    // ---- Phase 0: h = concat(x, ste) -> bf16 LDS [64][128]; ones row ----
#pragma unroll
    for (int l = 0; l < 8; ++l) {
        int idx = l * 256 + tid;            // 2048 float4s
        int t = idx >> 5, p = idx & 31;     // 32 float4 per row
        const float* src = (p < 16) ? xb : sb;
        float4 vv = *(const float4*)(src + (size_t)t * (Nn * Dd) + (p & 15) * 4);
        ushort4 st;
        st.x = f2bf(vv.x); st.y = f2bf(vv.y); st.z = f2bf(vv.z); st.w = f2bf(vv.w);
        *(ushort4*)&h[t * HS + p * 4] = st;
    }
    if (tid < 64) vT[64 * QS + tid] = 0x3F80;   // bf16 1.0 ones-row
    __syncthreads();                             // barrier 1: h, ones ready

    // ---- Phase 1: fused QKV (A-frags shared; B-frags from global) ----
    {
        f32x4 qa[4], ka[4], va[4];
#pragma unroll
        for (int ct = 0; ct < 4; ++ct) {
            int c = 16 * ct + l15;
            float b0 = bq[c], b1v = bk[c], b2v = bv_[c];
            qa[ct] = (f32x4){b0, b0, b0, b0};
            ka[ct] = (f32x4){b1v, b1v, b1v, b1v};
            va[ct] = (f32x4){b2v, b2v, b2v, b2v};
        }
        const u16* arow = &h[(16 * w + l15) * HS];
#pragma unroll
        for (int k0 = 0; k0 < 128; k0 += 32) {
            bf16x8 af = ldf(arow + k0 + qd * 8);
#pragma unroll
            for (int ct = 0; ct < 4; ++ct) {
                const int boff = (16 * ct + l15) * 128 + k0 + qd * 8;
                bf16x8 bq8 = ldf(&wq[boff]);
                qa[ct] = __builtin_amdgcn_mfma_f32_16x16x32_bf16(af, bq8, qa[ct], 0, 0, 0);
                bf16x8 bk8 = ldf(&wk[boff]);
                ka[ct] = __builtin_amdgcn_mfma_f32_16x16x32_bf16(af, bk8, ka[ct], 0, 0, 0);
                bf16x8 bv8 = ldf(&wv[boff]);
                va[ct] = __builtin_amdgcn_mfma_f32_16x16x32_bf16(af, bv8, va[ct], 0, 0, 0);
            }
        }
#pragma unroll
        for (int ct = 0; ct < 4; ++ct) {
            const int col = 16 * ct + l15;
#pragma unroll
            for (int r = 0; r < 4; ++r) {
                const int row = 16 * w + 4 * qd + r;
                qb[row * QS + col] = f2bf(fmaxf(qa[ct][r], 0.f) * QSCALE);
                kb[row * QS + col] = f2bf(fmaxf(ka[ct][r], 0.f));
                vT[col * QS + row] = f2bf(fmaxf(va[ct][r], 0.f));   // transposed
            }
        }
    }
    __syncthreads();    // barrier 2: kb/vT cross-wave; h dead (P/attnout overlay)

    // ---- Phase 2: attention. Wave w owns t-rows 16w..16w+15, 8 heads. ----
    u16* pb = sm + 4352 + 1088 * w;       // wave-private P slice [16][68]
    const bf16x8 z8 = zf8();
    const u16* qrow = &qb[(16 * w + l15) * QS];
#pragma unroll 1
    for (int h8 = 0; h8 < 64; h8 += 8) {
        // scores (K padded 8->32: quads 1-3 zeroed on both operands)
        bf16x8 af = (qd == 0) ? ldf(qrow + h8) : z8;
        f32x4 sv[4] = {{0,0,0,0},{0,0,0,0},{0,0,0,0},{0,0,0,0}};
#pragma unroll
        for (int ct = 0; ct < 4; ++ct) {
            bf16x8 bfr = (qd == 0) ? ldf(&kb[(16 * ct + l15) * QS + h8]) : z8;
            sv[ct] = __builtin_amdgcn_mfma_f32_16x16x32_bf16(af, bfr, sv[ct], 0, 0, 0);
        }
        // causal mask + exp2 (q pre-scaled by log2e/sqrt(d)); masked -> exact 0
        const int tr = 16 * w + 4 * qd;
#pragma unroll
        for (int ct = 0; ct < 4; ++ct) {
            const int sc = 16 * ct + l15;
#pragma unroll
            for (int r = 0; r < 4; ++r)
                sv[ct][r] = (sc <= tr + r) ? exp2f(sv[ct][r]) : 0.f;
        }
        // P (unnormalized) -> LDS (C-layout -> A-layout transform)
#pragma unroll
        for (int ct = 0; ct < 4; ++ct)
#pragma unroll
            for (int r = 0; r < 4; ++r)
                pb[(4 * qd + r) * QS + 16 * ct + l15] = f2bf(sv[ct][r]);
        // PV: cols 0-7 = head dims, col 8 = denom (ones row), 9-15 zero
        f32x4 o = {0, 0, 0, 0};
#pragma unroll
        for (int k0 = 0; k0 < 64; k0 += 32) {
            bf16x8 pa = ldf(&pb[l15 * QS + k0 + qd * 8]);
            const int vrow = (l15 < 8) ? (h8 + l15) : 64;
            bf16x8 vfr = (l15 <= 8) ? ldf(&vT[vrow * QS + k0 + qd * 8]) : z8;
            o = __builtin_amdgcn_mfma_f32_16x16x32_bf16(pa, vfr, o, 0, 0, 0);
        }
        const int dsrc = (lane & 48) | 8;   // lane l15==8 of own 16-group
#pragma unroll
        for (int r = 0; r < 4; ++r) {
            float den = __shfl(o[r], dsrc, 64);
            if (l15 < 8)
                attnout[(16 * w + 4 * qd + r) * QS + h8 + l15] =
                    f2bf(o[r] * __builtin_amdgcn_rcpf(den));
        }
    }
    // no barrier: FFN reads only same-wave-written LDS rows

    // ---- Phase 3: FFN ----
    mfma_gemm64<0>(attnout, QS, wsr + W1_OFF, b1, abuf, QS, nullptr, w, lane);
    float* ob = out + (((size_t)b * Tt) * Nn + n) * Dd;
    mfma_gemm64<1>(abuf, QS, wsr + W2_OFF, b2, nullptr, 0, ob, w, lane);
}

extern "C" void kernel_launch(void* const* d_in, const int* in_sizes, int n_in,
                              void* d_out, int out_size, void* d_ws, size_t ws_size,
                              hipStream_t stream) {
    const float* x   = (const float*)d_in[0];
    const float* ste = (const float*)d_in[1];
    const float* Wq  = (const float*)d_in[2];
    const float* bq  = (const float*)d_in[3];
    const float* Wk  = (const float*)d_in[4];
    const float* bk  = (const float*)d_in[5];
    const float* Wv  = (const float*)d_in[6];
    const float* bv  = (const float*)d_in[7];
    const float* W1  = (const float*)d_in[8];
    const float* b1  = (const float*)d_in[9];
    const float* W2  = (const float*)d_in[10];
    const float* b2  = (const float*)d_in[11];
    float* out = (float*)d_out;
    u16* ws = (u16*)d_ws;

    hipLaunchKernelGGL(prep_weights, dim3(128), dim3(256), 0, stream,
                       Wq, Wk, Wv, W1, W2, ws);
    hipLaunchKernelGGL(ta_fused_kernel, dim3(Bb * Nn), dim3(256), 0, stream,
                       x, ste, bq, bk, bv, b1, b2, (const u16*)ws, out);
}

// Round 4
// 313.665 us; speedup vs baseline: 1.0255x; 1.0255x over previous
//
#include <hip/hip_runtime.h>

// B=8, T=64, N=512, D=64, K=8 heads, d=8.
// One workgroup (256 thr = 4 waves) per (b,n). Full fusion in LDS.
// R4: weights pre-converted (prep kernel) AND preloaded once into VGPRs
// (col-ownership GEMMs: wave w owns cols 16w..16w+15, 16 B-frags total =
// 64 VGPRs, loaded at kernel start, overlapped with phase-0 staging).
// Causal wave-uniform skipping: wave w computes only score col-tiles ct<=w.

#define Bb 8
#define Tt 64
#define Nn 512
#define Dd 64

typedef unsigned short u16;
typedef unsigned int u32;
typedef __bf16 bf16x8 __attribute__((ext_vector_type(8)));
typedef float f32x4 __attribute__((ext_vector_type(4)));
typedef short s16x8 __attribute__((ext_vector_type(8)));

#define HS 136   // h row stride (shorts)
#define QS 68    // qb/kb/vT/attnout/P stride

// fused scale: 1/sqrt(8) * log2(e); softmax uses exp2
#define QSCALE 0.51006977f

// ws layout (u16): wqT[64][128]@0, wkT@8192, wvT@16384, w1T[64][64]@24576, w2T@28672
#define WQ_OFF 0
#define WK_OFF 8192
#define WV_OFF 16384
#define W1_OFF 24576
#define W2_OFF 28672

__device__ inline u16 f2bf(float f) {             // fp32 -> bf16 RNE
    u32 x = __float_as_uint(f);
    x += 0x7fffu + ((x >> 16) & 1u);
    return (u16)(x >> 16);
}
__device__ inline bf16x8 ldf(const u16* p) { return *(const bf16x8*)p; }
__device__ inline bf16x8 zf8() {
    s16x8 z = {0, 0, 0, 0, 0, 0, 0, 0};
    return __builtin_bit_cast(bf16x8, z);
}

// ---------------- prep: fp32 weights -> bf16 wT[c][k] in ws ----------------
__global__ __launch_bounds__(256)
void prep_weights(const float* __restrict__ Wq, const float* __restrict__ Wk,
                  const float* __restrict__ Wv, const float* __restrict__ W1,
                  const float* __restrict__ W2, u16* __restrict__ ws) {
    int t = blockIdx.x * 256 + threadIdx.x;       // 0..32767
    if (t < 24576) {                              // three 128x64 matrices
        int m = t >> 13, r = t & 8191;
        const float* W = (m == 0) ? Wq : (m == 1) ? Wk : Wv;
        int f = r >> 6, c = r & 63;
        ws[m * 8192 + c * 128 + f] = f2bf(W[r]);
    } else {                                      // two 64x64 matrices
        int t2 = t - 24576;
        int m = t2 >> 12, r = t2 & 4095;
        const float* W = m ? W2 : W1;
        int f = r >> 6, c = r & 63;
        ws[24576 + m * 4096 + c * 64 + f] = f2bf(W[r]);
    }
}

__global__ __launch_bounds__(256, 3)
void ta_fused_kernel(const float* __restrict__ x,  const float* __restrict__ ste,
                     const float* __restrict__ bq, const float* __restrict__ bk,
                     const float* __restrict__ bv_, const float* __restrict__ b1,
                     const float* __restrict__ b2, const u16* __restrict__ wsr,
                     float* __restrict__ out) {
    // LDS map (shorts), total 21828 (43656 B) -> 3 blocks/CU:
    //   h    [64][136] @ 0      (dead after QKV)
    //     attnout [64][68] @ 0         (overlay)
    //     P 4x[16][68]     @ 4352      (overlay, wave-private slices)
    //   qb   [64][68]  @ 8704   (abuf overlays after attention)
    //   kb   [64][68]  @ 13056
    //   vT   [65][68]  @ 17408  (row 64 = ones column -> softmax denom)
    __shared__ __align__(16) u16 sm[21828];
    u16* h       = sm;
    u16* qb      = sm + 8704;
    u16* kb      = sm + 13056;
    u16* vT      = sm + 17408;
    u16* attnout = sm;
    u16* abuf    = qb;

    const int tid  = threadIdx.x;
    const int w    = tid >> 6;
    const int lane = tid & 63;
    const int l15  = lane & 15, qd = lane >> 4;
    const int wl   = 16 * w + l15;      // this wave's owned column
    const int bid  = blockIdx.x;
    const int b = bid >> 9, n = bid & 511;

    const float* xb = x   + (((size_t)b * Tt) * Nn + n) * Dd;
    const float* sb = ste + (((size_t)b * Tt) * Nn + n) * Dd;

    // ---- Preload this wave's weight columns into registers (one-time) ----
    bf16x8 wqf[4], wkf[4], wvf[4], w1f[2], w2f[2];
    {
        const u16* pq = wsr + WQ_OFF + wl * 128 + qd * 8;
        const u16* pk = wsr + WK_OFF + wl * 128 + qd * 8;
        const u16* pv = wsr + WV_OFF + wl * 128 + qd * 8;
#pragma unroll
        for (int k0 = 0; k0 < 4; ++k0) {
            wqf[k0] = ldf(pq + 32 * k0);
            wkf[k0] = ldf(pk + 32 * k0);
            wvf[k0] = ldf(pv + 32 * k0);
        }
        const u16* p1 = wsr + W1_OFF + wl * 64 + qd * 8;
        const u16* p2 = wsr + W2_OFF + wl * 64 + qd * 8;
        w1f[0] = ldf(p1); w1f[1] = ldf(p1 + 32);
        w2f[0] = ldf(p2); w2f[1] = ldf(p2 + 32);
    }
    const float bqv = bq[wl], bkv = bk[wl], bvv = bv_[wl];
    const float b1v = b1[wl], b2v = b2[wl];

    // ---- Phase 0: h = concat(x, ste) -> bf16 LDS [64][128]; ones row ----
#pragma unroll
    for (int l = 0; l < 8; ++l) {
        int idx = l * 256 + tid;            // 2048 float4s
        int t = idx >> 5, p = idx & 31;     // 32 float4 per row
        const float* src = (p < 16) ? xb : sb;
        float4 vv = *(const float4*)(src + (size_t)t * (Nn * Dd) + (p & 15) * 4);
        ushort4 st;
        st.x = f2bf(vv.x); st.y = f2bf(vv.y); st.z = f2bf(vv.z); st.w = f2bf(vv.w);
        *(ushort4*)&h[t * HS + p * 4] = st;
    }
    if (tid < 64) vT[64 * QS + tid] = 0x3F80;   // bf16 1.0 ones row
    __syncthreads();                             // barrier 1: h ready

    // ---- Phase 1: QKV, col-ownership (B-frags in registers) ----
#pragma unroll
    for (int rt = 0; rt < 4; ++rt) {
        f32x4 qa = {bqv, bqv, bqv, bqv};
        f32x4 ka = {bkv, bkv, bkv, bkv};
        f32x4 va = {bvv, bvv, bvv, bvv};
        const u16* arow = &h[(16 * rt + l15) * HS + qd * 8];
#pragma unroll
        for (int k0 = 0; k0 < 4; ++k0) {
            bf16x8 af = ldf(arow + 32 * k0);
            qa = __builtin_amdgcn_mfma_f32_16x16x32_bf16(af, wqf[k0], qa, 0, 0, 0);
            ka = __builtin_amdgcn_mfma_f32_16x16x32_bf16(af, wkf[k0], ka, 0, 0, 0);
            va = __builtin_amdgcn_mfma_f32_16x16x32_bf16(af, wvf[k0], va, 0, 0, 0);
        }
#pragma unroll
        for (int r = 0; r < 4; ++r) {
            const int row = 16 * rt + 4 * qd + r;
            qb[row * QS + wl] = f2bf(fmaxf(qa[r], 0.f) * QSCALE);
            kb[row * QS + wl] = f2bf(fmaxf(ka[r], 0.f));
            vT[wl * QS + row] = f2bf(fmaxf(va[r], 0.f));   // transposed
        }
    }
    __syncthreads();    // barrier 2: qb/kb/vT cross-wave; h dead (overlay)

    // ---- Phase 2: attention. Wave w owns t-rows 16w..16w+15, 8 heads. ----
    u16* pb = sm + 4352 + 1088 * w;       // wave-private P slice [16][68]
    const bf16x8 z8 = zf8();
    const u16* qrow = &qb[(16 * w + l15) * QS];
    const int nct = w + 1;                 // col-tiles with unmasked entries
    // pre-zero always-masked P cols (done once; never rewritten)
    for (int ct = nct; ct < 4; ++ct)
#pragma unroll
        for (int r = 0; r < 4; ++r)
            pb[(4 * qd + r) * QS + 16 * ct + l15] = 0;

#pragma unroll 1
    for (int h8 = 0; h8 < 64; h8 += 8) {
        // scores for ct<=w only (K padded 8->32: quads 1-3 zeroed)
        bf16x8 af = (qd == 0) ? ldf(qrow + h8) : z8;
        f32x4 sv[4];
        for (int ct = 0; ct < nct; ++ct) {
            f32x4 zz = {0, 0, 0, 0};
            bf16x8 bfr = (qd == 0) ? ldf(&kb[(16 * ct + l15) * QS + h8]) : z8;
            sv[ct] = __builtin_amdgcn_mfma_f32_16x16x32_bf16(af, bfr, zz, 0, 0, 0);
        }
        // causal mask + exp2; masked -> exact 0
        const int tr = 16 * w + 4 * qd;
        for (int ct = 0; ct < nct; ++ct) {
            const int sc = 16 * ct + l15;
#pragma unroll
            for (int r = 0; r < 4; ++r)
                sv[ct][r] = (sc <= tr + r) ? exp2f(sv[ct][r]) : 0.f;
        }
        // P (unnormalized) -> LDS (C-layout -> A-layout transform)
        for (int ct = 0; ct < nct; ++ct)
#pragma unroll
            for (int r = 0; r < 4; ++r)
                pb[(4 * qd + r) * QS + 16 * ct + l15] = f2bf(sv[ct][r]);
        // PV: cols 0-7 = head dims, col 8 = denom (ones row)
        f32x4 o = {0, 0, 0, 0};
        {
            const int vrow = (l15 < 8) ? (h8 + l15) : 64;
            bf16x8 pa = ldf(&pb[l15 * QS + qd * 8]);
            bf16x8 vfr = ldf(&vT[vrow * QS + qd * 8]);
            if (l15 > 8) vfr = z8;
            o = __builtin_amdgcn_mfma_f32_16x16x32_bf16(pa, vfr, o, 0, 0, 0);
            if (nct > 2) {   // s-range 32..63 only populated for waves 2,3
                bf16x8 pa2 = ldf(&pb[l15 * QS + 32 + qd * 8]);
                bf16x8 vfr2 = ldf(&vT[vrow * QS + 32 + qd * 8]);
                if (l15 > 8) vfr2 = z8;
                o = __builtin_amdgcn_mfma_f32_16x16x32_bf16(pa2, vfr2, o, 0, 0, 0);
            }
        }
        const int dsrc = (lane & 48) | 8;   // lane with col 8 in own 16-group
#pragma unroll
        for (int r = 0; r < 4; ++r) {
            float den = __shfl(o[r], dsrc, 64);
            if (l15 < 8)
                attnout[(16 * w + 4 * qd + r) * QS + h8 + l15] =
                    f2bf(o[r] * __builtin_amdgcn_rcpf(den));
        }
    }
    __syncthreads();    // barrier 3: attnout cross-wave

    // ---- Phase 3: FFN, col-ownership (B-frags in registers) ----
#pragma unroll
    for (int rt = 0; rt < 4; ++rt) {
        f32x4 a1 = {b1v, b1v, b1v, b1v};
        const u16* arow = &attnout[(16 * rt + l15) * QS + qd * 8];
        a1 = __builtin_amdgcn_mfma_f32_16x16x32_bf16(ldf(arow), w1f[0], a1, 0, 0, 0);
        a1 = __builtin_amdgcn_mfma_f32_16x16x32_bf16(ldf(arow + 32), w1f[1], a1, 0, 0, 0);
#pragma unroll
        for (int r = 0; r < 4; ++r)
            abuf[(16 * rt + 4 * qd + r) * QS + wl] = f2bf(fmaxf(a1[r], 0.f));
    }
    __syncthreads();    // barrier 4: abuf cross-wave
    float* ob = out + (((size_t)b * Tt) * Nn + n) * Dd;
#pragma unroll
    for (int rt = 0; rt < 4; ++rt) {
        f32x4 a2 = {b2v, b2v, b2v, b2v};
        const u16* arow = &abuf[(16 * rt + l15) * QS + qd * 8];
        a2 = __builtin_amdgcn_mfma_f32_16x16x32_bf16(ldf(arow), w2f[0], a2, 0, 0, 0);
        a2 = __builtin_amdgcn_mfma_f32_16x16x32_bf16(ldf(arow + 32), w2f[1], a2, 0, 0, 0);
#pragma unroll
        for (int r = 0; r < 4; ++r)
            ob[(size_t)(16 * rt + 4 * qd + r) * (Nn * Dd) + wl] = a2[r];
    }
}

extern "C" void kernel_launch(void* const* d_in, const int* in_sizes, int n_in,
                              void* d_out, int out_size, void* d_ws, size_t ws_size,
                              hipStream_t stream) {
    const float* x   = (const float*)d_in[0];
    const float* ste = (const float*)d_in[1];
    const float* Wq  = (const float*)d_in[2];
    const float* bq  = (const float*)d_in[3];
    const float* Wk  = (const float*)d_in[4];
    const float* bk  = (const float*)d_in[5];
    const float* Wv  = (const float*)d_in[6];
    const float* bv  = (const float*)d_in[7];
    const float* W1  = (const float*)d_in[8];
    const float* b1  = (const float*)d_in[9];
    const float* W2  = (const float*)d_in[10];
    const float* b2  = (const float*)d_in[11];
    float* out = (float*)d_out;
    u16* ws = (u16*)d_ws;

    hipLaunchKernelGGL(prep_weights, dim3(128), dim3(256), 0, stream,
                       Wq, Wk, Wv, W1, W2, ws);
    hipLaunchKernelGGL(ta_fused_kernel, dim3(Bb * Nn), dim3(256), 0, stream,
                       x, ste, bq, bk, bv, b1, b2, (const u16*)ws, out);
}